// Round 1
// baseline (129.396 us; speedup 1.0000x reference)
//
#include <hip/hip_runtime.h>
#include <math.h>

// Problem constants (fixed by setup_inputs)
#define BATCH 8
#define HI 512
#define WI 512
#define HO 256
#define WO 256
#define PLANE (HI*WI)          // 262144 per channel
#define OPIX (HO*WO)           // 65536 output pixels per batch
#define LROWS 260              // image rows 2..261 staged
#define LCOLS 10               // cols [r-4, r+6) per row
#define LSTRIDE 33             // 10 cols * 3 ch, padded 30 -> 33 (odd: bank-conflict-free)
#define LDS_FLOATS (LROWS*LSTRIDE)

__global__ __launch_bounds__(256) void downsampler_kernel(
    const float* __restrict__ images,
    const float* __restrict__ kernels,
    const float* __restrict__ offx,
    const float* __restrict__ offy,
    float* __restrict__ out)
{
    __shared__ float simg[LDS_FLOATS];

    const int bid = blockIdx.x;
    const int b  = bid >> 8;      // batch
    const int ih = bid & 255;     // output row
    const int iw = threadIdx.x;   // output col

    // ---- Stage the diagonal image band into LDS ----
    // I(r, c, ch) for r in [2,262), c in [r-4, r+6), ch in [0,3)
    // simg[(r-2)*33 + (c-(r-4))*3 + ch]
    {
        const float* imb = images + (size_t)b * 3 * PLANE;
        const int total = 3 * LROWS * LCOLS;   // 7800
        for (int i = threadIdx.x; i < total; i += 256) {
            int ch  = i / (LROWS * LCOLS);
            int rem = i - ch * (LROWS * LCOLS);
            int rr  = rem / LCOLS;
            int cr  = rem - rr * LCOLS;
            int r = rr + 2;
            int c = r - 4 + cr;
            c = c < 0 ? 0 : (c > WI - 1 ? WI - 1 : c);
            simg[rr * LSTRIDE + cr * 3 + ch] = imb[ch * PLANE + r * WI + c];
        }
    }
    __syncthreads();

    const int pl  = ih * WO + iw;               // pixel-linear index in batch
    const int pl2 = (2 * pl) & (OPIX - 1);      // scrambled weight source pixel
    const bool flip = (pl < (OPIX / 2));        // first half: weight = x1-x = 1-frac

    const float* offxb = offx   + (size_t)b * 9 * OPIX;
    const float* offyb = offy   + (size_t)b * 9 * OPIX;
    const float* kernb = kernels + (size_t)b * 9 * OPIX;

    // ---- Scrambled weights: wx[t], wy[t], t = 2k+j, from pixels pl2 / pl2+1 ----
    float wx[18], wy[18];
    #pragma unroll
    for (int t = 0; t < 18; ++t) {
        const int sel = (t >= 9) ? 1 : 0;
        const int ks  = t - 9 * sel;            // source tap index
        const int p   = pl2 + sel;              // source pixel (never overflows: pl2 even, <=65534)
        const float uu  = (float)(p & (WO - 1)) + 0.5f;   // u[iw_src]
        const float kxf = (float)(ks / 3);
        const float kyf = (float)(ks - 3 * (ks / 3));
        // replicate reference fp32 op order: ((off + 1.5) + k?) + u
        const float cx = ((offxb[ks * OPIX + p] + 1.5f) + kxf) + uu;
        const float cy = ((offyb[ks * OPIX + p] + 1.5f) + kyf) + uu;
        const float fxw = cx - floorf(cx);      // exact (Sterbenz)
        const float fyw = cy - floorf(cy);
        wx[t] = flip ? (1.0f - fxw) : fxw;      // 1-frac exact == (floor+1)-cx
        wy[t] = flip ? (1.0f - fyw) : fyw;
    }

    // ---- Per-tap gather + scrambled-channel bilinear + kernel accumulation ----
    float acc0 = 0.f, acc1 = 0.f, acc2 = 0.f;
    const float uu_own = (float)iw + 0.5f;
    #pragma unroll
    for (int k = 0; k < 9; ++k) {
        const float kxf = (float)(k / 3);
        const float kyf = (float)(k - 3 * (k / 3));
        const float cx = ((offxb[k * OPIX + pl] + 1.5f) + kxf) + uu_own;
        const float cy = ((offyb[k * OPIX + pl] + 1.5f) + kyf) + uu_own;
        const int x0 = (int)floorf(cx);   // row, in [iw+2, iw+5]
        const int y0 = (int)floorf(cy);   // col, in [iw+2, iw+5]

        // LDS addressing: value I(r,c,ch) = simg[(r-2)*33 + (c-r+4)*3 + ch]
        const float* r0 = &simg[(x0 - 2) * LSTRIDE];  // row x0
        const float* r1 = &simg[(x0 - 1) * LSTRIDE];  // row x1 = x0+1
        const int c00 = (y0 - x0 + 4) * 3;  // (x0,y0) ; in-range [1,7]*3
        const int c01 = c00 + 3;            // (x0,y1)
        const int c10 = c00 - 3;            // (x1,y0): (y0 - (x0+1) + 4)*3
        const int c11 = c00;                // (x1,y1)

        const float Ia0 = r0[c00 + 0], Ia1 = r0[c00 + 1], Ia2 = r0[c00 + 2]; // (x0,y0)
        const float Ib0 = r0[c01 + 0], Ib1 = r0[c01 + 1], Ib2 = r0[c01 + 2]; // (x0,y1)
        const float Ic0 = r1[c10 + 0], Ic1 = r1[c10 + 1], Ic2 = r1[c10 + 2]; // (x1,y0)
        const float Id0 = r1[c11 + 0], Id1 = r1[c11 + 1], Id2 = r1[c11 + 2]; // (x1,y1)

        const float w0 = wx[2 * k], w1 = wx[2 * k + 1];
        const float v0 = wy[2 * k], v1 = wy[2 * k + 1];
        const float w0v0 = w0 * v0, w1v0 = w1 * v0, w0v1 = w0 * v1, w1v1 = w1 * v1;

        // scrambled channel/corner table (q = (6i+3j+c)%4, ch = (6i+3j+c)/4)
        const float p0 = w0v0 * Ib0 + w1v0 * Ic0 + w0v1 * Id1 + w1v1 * Ia2;
        const float p1 = w0v0 * Ia0 + w1v0 * Ib1 + w0v1 * Ic1 + w1v1 * Id2;
        const float p2 = w0v0 * Id0 + w1v0 * Ia1 + w0v1 * Ib2 + w1v1 * Ic2;

        const float kv = kernb[k * OPIX + pl];
        acc0 += kv * p0;
        acc1 += kv * p1;
        acc2 += kv * p2;
    }

    // ---- softround(out * 255) ----
    const float TWO_PI     = 6.28318530717958647692f;
    const float INV_TWO_PI = 0.15915494309189533577f;
    const size_t obase = ((size_t)b * OPIX + (size_t)pl) * 3;
    const float z0 = acc0 * 255.0f;
    const float z1 = acc1 * 255.0f;
    const float z2 = acc2 * 255.0f;
    out[obase + 0] = z0 - sinf(TWO_PI * z0) * INV_TWO_PI;
    out[obase + 1] = z1 - sinf(TWO_PI * z1) * INV_TWO_PI;
    out[obase + 2] = z2 - sinf(TWO_PI * z2) * INV_TWO_PI;
}

extern "C" void kernel_launch(void* const* d_in, const int* in_sizes, int n_in,
                              void* d_out, int out_size, void* d_ws, size_t ws_size,
                              hipStream_t stream) {
    const float* images  = (const float*)d_in[0];
    const float* kernels = (const float*)d_in[1];
    const float* offx    = (const float*)d_in[2];
    const float* offy    = (const float*)d_in[3];
    float* out = (float*)d_out;

    dim3 grid(BATCH * HO);   // 2048 blocks: one per (b, ih)
    dim3 block(WO);          // 256 threads: one per iw
    hipLaunchKernelGGL(downsampler_kernel, grid, block, 0, stream,
                       images, kernels, offx, offy, out);
}

// Round 2
// 120.116 us; speedup vs baseline: 1.0773x; 1.0773x over previous
//
#include <hip/hip_runtime.h>
#include <math.h>

// Problem constants (fixed by setup_inputs)
#define BATCH 8
#define HI 512
#define WI 512
#define HO 256
#define WO 256
#define PLANE (HI*WI)          // 262144 per channel
#define OPIX (HO*WO)           // 65536 output pixels per batch
// Block tile: 64 iw-cols x 4 ih-rows. Gather footprint for iw in [w0,w0+64):
// image rows/cols in [w0+2, w0+70) -> 68 rows, 10 cols per row, 3 channels.
#define LROWS 68
#define LCOLS 10
#define LSTRIDE 33             // 10*3=30 padded to 33 (odd: lane stride 33 -> bank+1)
#define LDS_FLOATS (LROWS*LSTRIDE)   // 2244 floats = 8976 B

__global__ __launch_bounds__(256) void downsampler_kernel(
    const float* __restrict__ images,
    const float* __restrict__ kernels,
    const float* __restrict__ offx,
    const float* __restrict__ offy,
    float* __restrict__ out)
{
    __shared__ float simg[LDS_FLOATS];

    const int blk = blockIdx.x;
    const int b    = blk >> 8;           // batch
    const int ihx  = (blk >> 2) & 63;    // ih-tile (4 rows each)
    const int w0   = (blk & 3) << 6;     // iw-tile base (64 cols)
    const int tid  = threadIdx.x;
    const int iw   = w0 + (tid & 63);
    const int ih   = (ihx << 2) + (tid >> 6);   // wave-uniform

    // ---- Stage the 68x10x3 image band into LDS ----
    // I(r, c, ch) = simg[(r-(w0+2))*33 + (c-(r-4))*3 + ch], r in [w0+2, w0+70)
    {
        const float* imb = images + (size_t)b * 3 * PLANE;
        const int total = LROWS * LCOLS * 3;   // 2040
        for (int i = tid; i < total; i += 256) {
            const int ch  = i / (LROWS * LCOLS);        // 0..2
            const int rem = i - ch * (LROWS * LCOLS);
            const int rr  = rem / LCOLS;
            const int cr  = rem - rr * LCOLS;
            const int r = w0 + 2 + rr;
            int c = r - 4 + cr;
            c = c < 0 ? 0 : (c > WI - 1 ? WI - 1 : c);
            simg[rr * LSTRIDE + cr * 3 + ch] = imb[ch * PLANE + r * WI + c];
        }
    }
    __syncthreads();

    const int pl  = ih * WO + iw;               // pixel-linear index in batch
    const int pl2 = (2 * pl) & (OPIX - 1);      // scrambled weight source pixel
    const bool flip = (pl < (OPIX / 2));        // wave-uniform (ih < 128)

    const float* offxb = offx    + (size_t)b * 9 * OPIX;
    const float* offyb = offy    + (size_t)b * 9 * OPIX;
    const float* kernb = kernels + (size_t)b * 9 * OPIX;

    const float uu_own = (float)iw + 0.5f;
    // u at the scrambled weight-source pixels pl2 / pl2+1
    const float uu_s0 = (float)((2 * iw) & (WO - 1)) + 0.5f;
    const float uu_s1 = (float)((2 * iw + 1) & (WO - 1)) + 0.5f;

    float acc0 = 0.f, acc1 = 0.f, acc2 = 0.f;

    #pragma unroll
    for (int k = 0; k < 9; ++k) {
        // ---- own coords -> gather corners ----
        const float kxf = (float)(k / 3);
        const float kyf = (float)(k - 3 * (k / 3));
        const float cx = ((offxb[k * OPIX + pl] + 1.5f) + kxf) + uu_own;
        const float cy = ((offyb[k * OPIX + pl] + 1.5f) + kyf) + uu_own;
        const int x0 = (int)floorf(cx);   // row, in [iw+2, iw+5]
        const int y0 = (int)floorf(cy);   // col, in [iw+2, iw+5]

        // ---- scrambled weights for this tap (t = 2k, 2k+1) ----
        const int ta = 2 * k;
        const int tb = 2 * k + 1;
        const int sel_a = (ta >= 9) ? 1 : 0;
        const int sel_b = (tb >= 9) ? 1 : 0;
        const int ks_a = ta - 9 * sel_a;
        const int ks_b = tb - 9 * sel_b;
        const float uu_a = sel_a ? uu_s1 : uu_s0;
        const float uu_b = sel_b ? uu_s1 : uu_s0;
        const float kxa = (float)(ks_a / 3), kya = (float)(ks_a - 3 * (ks_a / 3));
        const float kxb = (float)(ks_b / 3), kyb = (float)(ks_b - 3 * (ks_b / 3));

        const float cxa = ((offxb[ks_a * OPIX + pl2 + sel_a] + 1.5f) + kxa) + uu_a;
        const float cya = ((offyb[ks_a * OPIX + pl2 + sel_a] + 1.5f) + kya) + uu_a;
        const float cxb = ((offxb[ks_b * OPIX + pl2 + sel_b] + 1.5f) + kxb) + uu_b;
        const float cyb = ((offyb[ks_b * OPIX + pl2 + sel_b] + 1.5f) + kyb) + uu_b;

        const float fxa = cxa - floorf(cxa);   // exact (Sterbenz)
        const float fya = cya - floorf(cya);
        const float fxb = cxb - floorf(cxb);
        const float fyb = cyb - floorf(cyb);
        const float w0w = flip ? (1.0f - fxa) : fxa;   // wx[2k]
        const float w1w = flip ? (1.0f - fxb) : fxb;   // wx[2k+1]
        const float v0w = flip ? (1.0f - fya) : fya;   // wy[2k]
        const float v1w = flip ? (1.0f - fyb) : fyb;   // wy[2k+1]

        // ---- LDS gather: I(r,c,ch) = simg[(r-(w0+2))*33 + (c-r+4)*3 + ch] ----
        const float* r0 = &simg[(x0 - 2 - w0) * LSTRIDE];  // row x0
        const float* r1 = r0 + LSTRIDE;                     // row x1 = x0+1
        const int c00 = (y0 - x0 + 4) * 3;  // (x0,y0), index in [3,21]
        const int c01 = c00 + 3;            // (x0,y1)
        const int c10 = c00 - 3;            // (x1,y0)
        const int c11 = c00;                // (x1,y1)

        const float Ia0 = r0[c00 + 0], Ia1 = r0[c00 + 1], Ia2 = r0[c00 + 2];
        const float Ib0 = r0[c01 + 0], Ib1 = r0[c01 + 1], Ib2 = r0[c01 + 2];
        const float Ic0 = r1[c10 + 0], Ic1 = r1[c10 + 1], Ic2 = r1[c10 + 2];
        const float Id0 = r1[c11 + 0], Id1 = r1[c11 + 1], Id2 = r1[c11 + 2];

        const float w0v0 = w0w * v0w, w1v0 = w1w * v0w;
        const float w0v1 = w0w * v1w, w1v1 = w1w * v1w;

        // scrambled channel/corner table
        const float p0 = w0v0 * Ib0 + w1v0 * Ic0 + w0v1 * Id1 + w1v1 * Ia2;
        const float p1 = w0v0 * Ia0 + w1v0 * Ib1 + w0v1 * Ic1 + w1v1 * Id2;
        const float p2 = w0v0 * Id0 + w1v0 * Ia1 + w0v1 * Ib2 + w1v1 * Ic2;

        const float kv = kernb[k * OPIX + pl];
        acc0 += kv * p0;
        acc1 += kv * p1;
        acc2 += kv * p2;
    }

    // ---- softround(out * 255) ----
    const float TWO_PI     = 6.28318530717958647692f;
    const float INV_TWO_PI = 0.15915494309189533577f;
    const size_t obase = ((size_t)b * OPIX + (size_t)pl) * 3;
    const float z0 = acc0 * 255.0f;
    const float z1 = acc1 * 255.0f;
    const float z2 = acc2 * 255.0f;
    out[obase + 0] = z0 - sinf(TWO_PI * z0) * INV_TWO_PI;
    out[obase + 1] = z1 - sinf(TWO_PI * z1) * INV_TWO_PI;
    out[obase + 2] = z2 - sinf(TWO_PI * z2) * INV_TWO_PI;
}

extern "C" void kernel_launch(void* const* d_in, const int* in_sizes, int n_in,
                              void* d_out, int out_size, void* d_ws, size_t ws_size,
                              hipStream_t stream) {
    const float* images  = (const float*)d_in[0];
    const float* kernels = (const float*)d_in[1];
    const float* offx    = (const float*)d_in[2];
    const float* offy    = (const float*)d_in[3];
    float* out = (float*)d_out;

    dim3 grid(BATCH * 64 * 4);   // 2048 blocks: (b, ih-tile of 4, iw-tile of 64)
    dim3 block(256);             // 64 iw-lanes x 4 ih-rows
    hipLaunchKernelGGL(downsampler_kernel, grid, block, 0, stream,
                       images, kernels, offx, offy, out);
}

// Round 3
// 116.242 us; speedup vs baseline: 1.1132x; 1.0333x over previous
//
#include <hip/hip_runtime.h>
#include <math.h>

// Problem constants (fixed by setup_inputs)
#define BATCH 8
#define HI 512
#define WI 512
#define HO 256
#define WO 256
#define PLANE (HI*WI)          // 262144 per channel
#define OPIX (HO*WO)           // 65536 output pixels per batch
// Block tile: 64 iw-cols x 8 ih-rows (2 rows per thread).
// Gather footprint for iw in [w0,w0+64): rows/cols in [w0+2, w0+70).
#define LROWS 68
#define LCOLS 10
#define LSTRIDE 33             // 10*3=30 padded to 33 (odd stride: conflict-free rows)
#define LDS_FLOATS (LROWS*LSTRIDE)   // 2244 floats = 8976 B

__global__ __launch_bounds__(256, 4) void downsampler_kernel(
    const float* __restrict__ images,
    const float* __restrict__ kernels,
    const float* __restrict__ offx,
    const float* __restrict__ offy,
    float* __restrict__ out)
{
    __shared__ float simg[LDS_FLOATS];

    const int blk  = blockIdx.x;          // 1024 blocks
    const int b    = blk >> 7;            // batch
    const int ihx  = (blk >> 2) & 31;     // ih-tile (8 rows each)
    const int w0   = (blk & 3) << 6;      // iw-tile base (64 cols)
    const int tid  = threadIdx.x;
    const int lane = tid & 63;
    const int g    = tid >> 6;            // wave id 0..3
    const int iw   = w0 + lane;

    // ---- Stage the 68x10x3 image band into LDS ----
    // I(r, c, ch) = simg[(r-(w0+2))*33 + (c-(r-4))*3 + ch], r in [w0+2, w0+70)
    {
        const float* imb = images + (size_t)b * 3 * PLANE;
        const int total = LROWS * LCOLS * 3;   // 2040
        for (int i = tid; i < total; i += 256) {
            const int ch  = i / (LROWS * LCOLS);
            const int rem = i - ch * (LROWS * LCOLS);
            const int rr  = rem / LCOLS;
            const int cr  = rem - rr * LCOLS;
            const int r = w0 + 2 + rr;
            int c = r - 4 + cr;
            c = c < 0 ? 0 : c;   // upper clamp provably inactive (c <= 266)
            simg[rr * LSTRIDE + cr * 3 + ch] = imb[ch * PLANE + r * WI + c];
        }
    }
    __syncthreads();

    const bool flip = (ihx < 16);          // ih < 128, uniform per block
    const float* offxb = offx    + (size_t)b * 9 * OPIX;
    const float* offyb = offy    + (size_t)b * 9 * OPIX;
    const float* kernb = kernels + (size_t)b * 9 * OPIX;

    const float uu_own = (float)iw + 0.5f;
    const float uu_s0  = (float)((2 * iw) & 255) + 0.5f;  // u at scrambled pixel 2pl
    const float uu_s1  = uu_s0 + 1.0f;                     // u at pixel 2pl+1

    const float TWO_PI_INV = 0.15915494309189533577f;

    #pragma unroll
    for (int p = 0; p < 2; ++p) {
        const int ih = (ihx << 3) + (g << 1) + p;
        const int pl = ih * WO + iw;                 // pixel-linear index
        const int pix2 = pl & (OPIX / 2 - 1);        // float2 index: (2pl mod 65536)/2

        // ---- scrambled weight sources: float2 covers pixels (2pl, 2pl+1) ----
        float2 vx[9], vy[9];
        #pragma unroll
        for (int ks = 0; ks < 9; ++ks) {
            vx[ks] = ((const float2*)(offxb + ks * OPIX))[pix2];
            vy[ks] = ((const float2*)(offyb + ks * OPIX))[pix2];
        }
        float wx[18], wy[18];
        #pragma unroll
        for (int t = 0; t < 18; ++t) {
            const int sel = (t >= 9) ? 1 : 0;
            const int ks  = t - 9 * sel;
            const float uu  = sel ? uu_s1 : uu_s0;
            const float oxv = sel ? vx[ks].y : vx[ks].x;
            const float oyv = sel ? vy[ks].y : vy[ks].x;
            const float kxf = (float)(ks / 3);
            const float kyf = (float)(ks - 3 * (ks / 3));
            // reference fp32 op order: ((off + 1.5) + k?) + u
            const float cxx = ((oxv + 1.5f) + kxf) + uu;
            const float cyy = ((oyv + 1.5f) + kyf) + uu;
            const float fx = cxx - floorf(cxx);   // exact (Sterbenz)
            const float fy = cyy - floorf(cyy);
            wx[t] = flip ? (1.0f - fx) : fx;
            wy[t] = flip ? (1.0f - fy) : fy;
        }

        // ---- per-tap gather + scrambled-channel bilinear + kernel accum ----
        float acc0 = 0.f, acc1 = 0.f, acc2 = 0.f;
        #pragma unroll
        for (int k = 0; k < 9; ++k) {
            const float kxf = (float)(k / 3);
            const float kyf = (float)(k - 3 * (k / 3));
            const float cx = ((offxb[k * OPIX + pl] + 1.5f) + kxf) + uu_own;
            const float cy = ((offyb[k * OPIX + pl] + 1.5f) + kyf) + uu_own;
            const int x0 = (int)floorf(cx);   // row in [iw+2, iw+5]
            const int y0 = (int)floorf(cy);   // col in [iw+2, iw+5]

            const float* r0 = &simg[(x0 - 2 - w0) * LSTRIDE];  // row x0
            const float* r1 = r0 + LSTRIDE;                     // row x1 = x0+1
            const int c00 = (y0 - x0 + 4) * 3;   // in [3,21]
            const int c01 = c00 + 3;
            const int c10 = c00 - 3;
            const int c11 = c00;

            const float Ia0 = r0[c00 + 0], Ia1 = r0[c00 + 1], Ia2 = r0[c00 + 2];
            const float Ib0 = r0[c01 + 0], Ib1 = r0[c01 + 1], Ib2 = r0[c01 + 2];
            const float Ic0 = r1[c10 + 0], Ic1 = r1[c10 + 1], Ic2 = r1[c10 + 2];
            const float Id0 = r1[c11 + 0], Id1 = r1[c11 + 1], Id2 = r1[c11 + 2];

            const float w0w = wx[2 * k], w1w = wx[2 * k + 1];
            const float v0w = wy[2 * k], v1w = wy[2 * k + 1];
            const float w0v0 = w0w * v0w, w1v0 = w1w * v0w;
            const float w0v1 = w0w * v1w, w1v1 = w1w * v1w;

            // scrambled channel/corner table
            const float p0 = w0v0 * Ib0 + w1v0 * Ic0 + w0v1 * Id1 + w1v1 * Ia2;
            const float p1 = w0v0 * Ia0 + w1v0 * Ib1 + w0v1 * Ic1 + w1v1 * Id2;
            const float p2 = w0v0 * Id0 + w1v0 * Ia1 + w0v1 * Ib2 + w1v1 * Ic2;

            const float kv = kernb[k * OPIX + pl];
            acc0 += kv * p0;
            acc1 += kv * p1;
            acc2 += kv * p2;
        }

        // ---- softround(out * 255) via HW sin (input in revolutions) ----
        const size_t obase = ((size_t)b * OPIX + (size_t)pl) * 3;
        const float z0 = acc0 * 255.0f;
        const float z1 = acc1 * 255.0f;
        const float z2 = acc2 * 255.0f;
        const float r0s = z0 - rintf(z0);   // exact; sin(2*pi*z) = sin(2*pi*r)
        const float r1s = z1 - rintf(z1);
        const float r2s = z2 - rintf(z2);
        out[obase + 0] = z0 - __builtin_amdgcn_sinf(r0s) * TWO_PI_INV;
        out[obase + 1] = z1 - __builtin_amdgcn_sinf(r1s) * TWO_PI_INV;
        out[obase + 2] = z2 - __builtin_amdgcn_sinf(r2s) * TWO_PI_INV;
    }
}

extern "C" void kernel_launch(void* const* d_in, const int* in_sizes, int n_in,
                              void* d_out, int out_size, void* d_ws, size_t ws_size,
                              hipStream_t stream) {
    const float* images  = (const float*)d_in[0];
    const float* kernels = (const float*)d_in[1];
    const float* offx    = (const float*)d_in[2];
    const float* offy    = (const float*)d_in[3];
    float* out = (float*)d_out;

    dim3 grid(BATCH * 32 * 4);   // 1024 blocks: (b, ih-tile of 8, iw-tile of 64)
    dim3 block(256);             // 64 iw-lanes x 4 waves, 2 ih-rows per thread
    hipLaunchKernelGGL(downsampler_kernel, grid, block, 0, stream,
                       images, kernels, offx, offy, out);
}